// Round 6
// baseline (1115.195 us; speedup 1.0000x reference)
//
#include <hip/hip_runtime.h>
#include <stdint.h>

#define NDIM   1024
#define NHEADS 8
#define NHD    128
#define NINNER 192
#define NFF    2730
#define NFFP   2816
#define NB     8
#define NL     2048
#define NBL    16384
#define NSTATE (NB * NHEADS * NINNER)   // 12288

typedef short  short8 __attribute__((ext_vector_type(8)));
typedef float  f32x4  __attribute__((ext_vector_type(4)));

__device__ __forceinline__ unsigned short f2bf(float f) {
  union { float f; uint32_t u; } v; v.f = f;
  uint32_t r = (v.u + 0x7FFFu + ((v.u >> 16) & 1u)) >> 16;
  return (unsigned short)r;
}

__device__ __forceinline__ void gload16(const void* g, void* l) {
  __builtin_amdgcn_global_load_lds(
      (const __attribute__((address_space(1))) uint32_t*)g,
      (__attribute__((address_space(3))) uint32_t*)l, 16, 0, 0);
}

__device__ __forceinline__ f32x4 mfma_bf16(short8 a, short8 b, f32x4 c) {
  return __builtin_amdgcn_mfma_f32_16x16x32_bf16(a, b, c, 0, 0, 0);
}

// ---- per-row rms scale: rscale[row] = 32 / max(||x_row||, 1e-12) -------------
__global__ __launch_bounds__(256) void rscale_kernel(
    const float* __restrict__ xin, float* __restrict__ rscale) {
  int row = blockIdx.x, t = threadIdx.x;
  float4 v = ((const float4*)(xin + (size_t)row * NDIM))[t];
  float ss = v.x * v.x + v.y * v.y + v.z * v.z + v.w * v.w;
  #pragma unroll
  for (int off = 32; off > 0; off >>= 1) ss += __shfl_xor(ss, off, 64);
  __shared__ float wss[4];
  if ((t & 63) == 0) wss[t >> 6] = ss;
  __syncthreads();
  if (t == 0) {
    ss = wss[0] + wss[1] + wss[2] + wss[3];
    rscale[row] = 32.0f / fmaxf(sqrtf(ss), 1e-12f);
  }
}

// ---- full rmsnorm -> bf16 (FFN input) ----------------------------------------
__global__ __launch_bounds__(256) void rms_bf16_kernel(
    const float* __restrict__ xin, const float* __restrict__ gamma,
    unsigned short* __restrict__ outb) {
  int row = blockIdx.x, t = threadIdx.x;
  float4 v = ((const float4*)(xin + (size_t)row * NDIM))[t];
  float ss = v.x * v.x + v.y * v.y + v.z * v.z + v.w * v.w;
  #pragma unroll
  for (int off = 32; off > 0; off >>= 1) ss += __shfl_xor(ss, off, 64);
  __shared__ float wss[4];
  if ((t & 63) == 0) wss[t >> 6] = ss;
  __syncthreads();
  ss = wss[0] + wss[1] + wss[2] + wss[3];
  float scale = 32.0f / fmaxf(sqrtf(ss), 1e-12f);
  float4 gv = ((const float4*)gamma)[t];
  ushort4 ob;
  ob.x = f2bf(v.x * scale * (1.0f + gv.x));
  ob.y = f2bf(v.y * scale * (1.0f + gv.y));
  ob.z = f2bf(v.z * scale * (1.0f + gv.z));
  ob.w = f2bf(v.w * scale * (1.0f + gv.w));
  ((ushort4*)outb)[(size_t)row * 256 + t] = ob;
}

// ---- input projections (fp32: spike round() is discontinuous) ----------------
// out layout: [(h*8 + b)*CL + ll]*192 + n   (per-(h,b) contiguous planes)
__global__ __launch_bounds__(256) void inproj_kernel(
    const float* __restrict__ x, const float* __restrict__ rscale,
    const float* __restrict__ gamma, const float* __restrict__ gate_W,
    const float* __restrict__ cand_W, float* __restrict__ gcb,
    float* __restrict__ ccb, int l_base, int LCL) {
  __shared__ float lA[64 * NHD];   // 32 KB normalized x tile [64 m][128 k]
  __shared__ float lW[64 * NHD];   // 32 KB weight tile, swizzled [64 n][128 k]
  int mt = blockIdx.x, h = blockIdx.y, z = blockIdx.z;
  int branch = z / 3, nt = z % 3, n0 = nt * 64;
  const float* W = (branch == 0 ? gate_W : cand_W)
                 + (size_t)h * NINNER * NHD + (size_t)n0 * NHD;
  float* outp = (branch == 0 ? gcb : ccb);
  int t = threadIdx.x;
  #pragma unroll
  for (int i = 0; i < 8; i++) {
    int c = t + i * 256;
    int r = c >> 5, c4 = c & 31;
    int m = mt * 64 + r, ll = m >> 3, b = m & 7;
    int xrow = b * NL + l_base + ll;
    float4 xv = *(const float4*)(x + (size_t)xrow * NDIM + h * NHD + c4 * 4);
    float rs = rscale[xrow];
    float4 gv = *(const float4*)(gamma + h * NHD + c4 * 4);
    float4 o;
    o.x = xv.x * rs * (1.0f + gv.x);
    o.y = xv.y * rs * (1.0f + gv.y);
    o.z = xv.z * rs * (1.0f + gv.z);
    o.w = xv.w * rs * (1.0f + gv.w);
    *(float4*)&lA[r * NHD + c4 * 4] = o;
    *(float4*)&lW[r * NHD + (((c4 ^ (r & 7)) & 31) * 4)] =
        *(const float4*)(W + (size_t)r * NHD + c4 * 4);
  }
  __syncthreads();
  int tr = t >> 4, tc = t & 15;
  int swz = (tc & 7) << 2;
  float acc[4][4] = {};
  #pragma unroll 4
  for (int k4 = 0; k4 < 32; k4++) {
    float4 a[4];
    #pragma unroll
    for (int m = 0; m < 4; m++) a[m] = *(float4*)&lA[(tr * 4 + m) * NHD + k4 * 4];
    #pragma unroll
    for (int j = 0; j < 4; j++) {
      int rowb = (tc + 16 * j) * NHD;
      float w0 = lW[rowb + ((k4 * 4 + 0) ^ swz)];
      float w1 = lW[rowb + ((k4 * 4 + 1) ^ swz)];
      float w2 = lW[rowb + ((k4 * 4 + 2) ^ swz)];
      float w3 = lW[rowb + ((k4 * 4 + 3) ^ swz)];
      #pragma unroll
      for (int m = 0; m < 4; m++) {
        acc[m][j] = fmaf(a[m].x, w0, acc[m][j]);
        acc[m][j] = fmaf(a[m].y, w1, acc[m][j]);
        acc[m][j] = fmaf(a[m].z, w2, acc[m][j]);
        acc[m][j] = fmaf(a[m].w, w3, acc[m][j]);
      }
    }
  }
  #pragma unroll
  for (int m = 0; m < 4; m++) {
    int mm = mt * 64 + tr * 4 + m;
    int ll = mm >> 3, b = mm & 7;
    size_t rowo = ((size_t)((h * NB + b) << LCL) + ll) * NINNER + n0 + tc;
    #pragma unroll
    for (int j = 0; j < 4; j++) outp[rowo + 16 * j] = acc[m][j];
  }
}

// ---- sequential spiking minGRU scan ------------------------------------------
// 192 blocks (one per (b,h,third)) x 64 threads: 3x the CU coverage of the
// old 64x192 shape; prefetch depth 32 covers ~900cy HBM latency.
__global__ __launch_bounds__(64) void scan_kernel(
    const float* __restrict__ gcb, const float* __restrict__ ccb,
    const float* __restrict__ gbr, const float* __restrict__ gth,
    const float* __restrict__ cbr, const float* __restrict__ cth,
    unsigned short* __restrict__ hbuf, float* __restrict__ state,
    int first, int CL, int LCL) {
  int bh = blockIdx.x / 3, third = blockIdx.x % 3;
  int b = bh >> 3, h = bh & 7;
  int i = third * 64 + threadIdx.x;
  int pi = h * NINNER + i;
  float beta_g = 1.0f / (1.0f + expf(-gbr[pi]));
  float beta_c = 1.0f / (1.0f + expf(-cbr[pi]));
  float thg = gth[pi], thc = cth[pi];
  size_t sbase = ((size_t)(b * NHEADS + h)) * NINNER + i;
  size_t pbase = ((size_t)((h * NB + b) << LCL)) * NINNER + i;
  const float* pg = gcb + pbase;
  const float* pc = ccb + pbase;
  unsigned short* ph = hbuf + pbase;
  float gm, cm, hs;
  if (first) { gm = 0.f; cm = 0.f; hs = 0.f; }
  else { gm = state[sbase]; cm = state[NSTATE + sbase]; hs = state[2 * NSTATE + sbase]; }
  const int CH = 32;
  float gq[CH], cq[CH];
  #pragma unroll
  for (int u = 0; u < CH; u++) { gq[u] = pg[u * NINNER]; cq[u] = pc[u * NINNER]; }
  int NIT = CL / CH;
  for (int ch = 0; ch < NIT; ch++) {
    float gn[CH], cn[CH];
    bool more = (ch + 1) < NIT;
    if (more) {
      size_t nb = (size_t)(ch + 1) * CH * NINNER;
      #pragma unroll
      for (int u = 0; u < CH; u++) { gn[u] = pg[nb + u * NINNER]; cn[u] = pc[nb + u * NINNER]; }
    }
    #pragma unroll
    for (int u = 0; u < CH; u++) {
      gm = fmaf(beta_g, gm, gq[u]);
      float gs = fminf(fmaxf(rintf(gm), -1.f), 1.f);
      gm -= gs * thg;
      float z = (gs + 1.f) * 0.5f;
      cm = fmaf(beta_c, cm, cq[u]);
      float cs = fminf(fmaxf(rintf(cm), -1.f), 1.f);
      cm -= cs * thc;
      hs = (1.f - z) * hs + z * cs;
      ph[((size_t)(ch * CH + u)) * NINNER] = f2bf(hs);
    }
    if (more) {
      #pragma unroll
      for (int u = 0; u < CH; u++) { gq[u] = gn[u]; cq[u] = cn[u]; }
    }
  }
  state[sbase] = gm; state[NSTATE + sbase] = cm; state[2 * NSTATE + sbase] = hs;
}

// ---- output projection as bf16 MFMA + residual: x2 = x + h @ out_W^T ---------
__global__ __launch_bounds__(256) void outproj_kernel(
    const unsigned short* __restrict__ hbuf, const unsigned short* __restrict__ wob,
    const float* __restrict__ x, float* __restrict__ x2, int l_base, int LCL) {
  __shared__ short lA[128 * 32], lB[128 * 32];  // 16 KB
  int t = threadIdx.x, lane = t & 63, wave = t >> 6;
  int wr = wave >> 1, wc = wave & 1;
  int m0 = blockIdx.x * 128;
  int h = blockIdx.y;
  const unsigned short* Ab = hbuf + ((size_t)(h * NB) << LCL) * NINNER;
  const unsigned short* Bb = wob + (size_t)h * NHD * NINNER;
  f32x4 z4 = {0.f, 0.f, 0.f, 0.f};
  f32x4 acc[4][4];
  #pragma unroll
  for (int i = 0; i < 4; i++)
    #pragma unroll
    for (int j = 0; j < 4; j++) acc[i][j] = z4;
  int rl = lane & 15, kq = (lane >> 4) * 8;
  for (int ks = 0; ks < NINNER / 32; ks++) {
    int k0 = ks * 32;
    #pragma unroll
    for (int it = 0; it < 2; it++) {
      int c = t + it * 256;
      int r = c >> 2, c8 = (c & 3) * 8;
      gload16(Ab + (size_t)(m0 + r) * NINNER + k0 + c8, &lA[c * 8]);
      gload16(Bb + (size_t)r * NINNER + k0 + c8, &lB[c * 8]);
    }
    __syncthreads();
    short8 a[4], bb[4];
    #pragma unroll
    for (int mi = 0; mi < 4; mi++)
      a[mi] = *(const short8*)&lA[(wr * 64 + mi * 16 + rl) * 32 + kq];
    #pragma unroll
    for (int ni = 0; ni < 4; ni++)
      bb[ni] = *(const short8*)&lB[(wc * 64 + ni * 16 + rl) * 32 + kq];
    #pragma unroll
    for (int mi = 0; mi < 4; mi++)
      #pragma unroll
      for (int ni = 0; ni < 4; ni++)
        acc[mi][ni] = mfma_bf16(a[mi], bb[ni], acc[mi][ni]);
    __syncthreads();
  }
  int CLm1 = (1 << LCL) - 1;
  #pragma unroll
  for (int mi = 0; mi < 4; mi++)
    #pragma unroll
    for (int ni = 0; ni < 4; ni++) {
      int rowl = m0 + wr * 64 + mi * 16 + (lane >> 4) * 4;
      int col = wc * 64 + ni * 16 + rl;
      #pragma unroll
      for (int r = 0; r < 4; r++) {
        int rr = rowl + r;
        int b = rr >> LCL, ll = rr & CLm1;
        size_t off = ((size_t)(b * NL + l_base + ll)) * NDIM + h * NHD + col;
        x2[off] = x[off] + acc[mi][ni][r];
      }
    }
}

// ---- weight packs ------------------------------------------------------------
__global__ __launch_bounds__(256) void pack_gu_kernel(
    const float* __restrict__ ffg, const float* __restrict__ ffu,
    unsigned short* __restrict__ wg, unsigned short* __restrict__ wu) {
  int row = blockIdx.x, t = threadIdx.x;
  const float* src = (blockIdx.y == 0) ? ffg : ffu;
  unsigned short* dst = (blockIdx.y == 0) ? wg : wu;
  ushort4 o;
  if (row < NFF) {
    float4 v = *(const float4*)(src + (size_t)row * NDIM + t * 4);
    o.x = f2bf(v.x); o.y = f2bf(v.y); o.z = f2bf(v.z); o.w = f2bf(v.w);
  } else { o.x = 0; o.y = 0; o.z = 0; o.w = 0; }
  *(ushort4*)(dst + (size_t)row * NDIM + t * 4) = o;
}

__global__ __launch_bounds__(256) void pack_d_kernel(
    const float* __restrict__ ffd, unsigned short* __restrict__ wd) {
  int row = blockIdx.x;
  for (int c = threadIdx.x; c < NFFP; c += 256) {
    float v = (c < NFF) ? ffd[(size_t)row * NFF + c] : 0.0f;
    wd[(size_t)row * NFFP + c] = f2bf(v);
  }
}

__global__ __launch_bounds__(256) void pack_flat_kernel(
    const float* __restrict__ src, unsigned short* __restrict__ dst, int n) {
  int i = blockIdx.x * 256 + threadIdx.x;
  if (i < n) dst[i] = f2bf(src[i]);
}

// ---- FFN gate+up bf16 MFMA GEMM, fused silu(g)*u, BK=64 ----------------------
// 128(M) x 64(N) tile; per-wave 64x32 dual-acc. BK=64 halves barrier events.
__global__ __launch_bounds__(256) void gateup_kernel(
    const unsigned short* __restrict__ fnb, const unsigned short* __restrict__ wg,
    const unsigned short* __restrict__ wu, unsigned short* __restrict__ act,
    int m_base, int nwg) {
  __shared__ short lA[128 * 64], lG[64 * 64], lU[64 * 64];  // 32 KB
  int q = nwg >> 3;
  int hw = blockIdx.x;
  int work = (hw & 7) * q + (hw >> 3);
  int mt = work / 44, ntl = work % 44;
  int t = threadIdx.x, lane = t & 63, wave = t >> 6;
  int wr = wave >> 1, wc = wave & 1;
  int m0l = mt * 128;
  int m0g = m_base + m0l;
  int n0 = ntl * 64;
  f32x4 z4 = {0.f, 0.f, 0.f, 0.f};
  f32x4 accg[4][2], accu[4][2];
  #pragma unroll
  for (int i = 0; i < 4; i++)
    #pragma unroll
    for (int j = 0; j < 2; j++) { accg[i][j] = z4; accu[i][j] = z4; }
  int rl = lane & 15, kq = (lane >> 4) * 8;
  for (int ks = 0; ks < NDIM / 64; ks++) {
    int k0 = ks * 64;
    #pragma unroll
    for (int it = 0; it < 4; it++) {         // A: 128 rows x 64 k
      int c = t + it * 256;
      int r = c >> 3, c8 = (c & 7) * 8;
      gload16(fnb + (size_t)(m0g + r) * NDIM + k0 + c8, &lA[c * 8]);
    }
    #pragma unroll
    for (int it = 0; it < 2; it++) {         // G/U: 64 rows x 64 k each
      int c = t + it * 256;
      int r = c >> 3, c8 = (c & 7) * 8;
      gload16(wg + (size_t)(n0 + r) * NDIM + k0 + c8, &lG[c * 8]);
      gload16(wu + (size_t)(n0 + r) * NDIM + k0 + c8, &lU[c * 8]);
    }
    __syncthreads();
    #pragma unroll
    for (int kh = 0; kh < 2; kh++) {
      int ko = kh * 32 + kq;
      short8 a[4], bg[2], bu[2];
      #pragma unroll
      for (int mi = 0; mi < 4; mi++)
        a[mi] = *(const short8*)&lA[(wr * 64 + mi * 16 + rl) * 64 + ko];
      #pragma unroll
      for (int ni = 0; ni < 2; ni++) {
        bg[ni] = *(const short8*)&lG[(wc * 32 + ni * 16 + rl) * 64 + ko];
        bu[ni] = *(const short8*)&lU[(wc * 32 + ni * 16 + rl) * 64 + ko];
      }
      #pragma unroll
      for (int mi = 0; mi < 4; mi++)
        #pragma unroll
        for (int ni = 0; ni < 2; ni++) {
          accg[mi][ni] = mfma_bf16(a[mi], bg[ni], accg[mi][ni]);
          accu[mi][ni] = mfma_bf16(a[mi], bu[ni], accu[mi][ni]);
        }
    }
    __syncthreads();
  }
  #pragma unroll
  for (int mi = 0; mi < 4; mi++)
    #pragma unroll
    for (int ni = 0; ni < 2; ni++) {
      int rowl = m0l + wr * 64 + mi * 16 + (lane >> 4) * 4;
      int col = n0 + wc * 32 + ni * 16 + rl;
      #pragma unroll
      for (int r = 0; r < 4; r++) {
        float g = accg[mi][ni][r], u = accu[mi][ni][r];
        float s = g / (1.0f + expf(-g)) * u;
        act[(size_t)(rowl + r) * NFFP + col] = f2bf(s);
      }
    }
}

// ---- FFN down bf16 MFMA GEMM + residual, BK=64 -------------------------------
__global__ __launch_bounds__(256) void down_kernel(
    const unsigned short* __restrict__ act, const unsigned short* __restrict__ wd,
    const float* resid, float* outp, int m_base, int nwg) {
  __shared__ short lA[128 * 64], lB[128 * 64];  // 32 KB
  int q = nwg >> 3;
  int hw = blockIdx.x;
  int work = (hw & 7) * q + (hw >> 3);
  int mt = work >> 3, ntl = work & 7;
  int t = threadIdx.x, lane = t & 63, wave = t >> 6;
  int wr = wave >> 1, wc = wave & 1;
  int m0l = mt * 128;
  int n0 = ntl * 128;
  f32x4 z4 = {0.f, 0.f, 0.f, 0.f};
  f32x4 acc[4][4];
  #pragma unroll
  for (int i = 0; i < 4; i++)
    #pragma unroll
    for (int j = 0; j < 4; j++) acc[i][j] = z4;
  int rl = lane & 15, kq = (lane >> 4) * 8;
  for (int ks = 0; ks < NFFP / 64; ks++) {
    int k0 = ks * 64;
    #pragma unroll
    for (int it = 0; it < 4; it++) {
      int c = t + it * 256;
      int r = c >> 3, c8 = (c & 7) * 8;
      gload16(act + (size_t)(m0l + r) * NFFP + k0 + c8, &lA[c * 8]);
      gload16(wd  + (size_t)(n0 + r) * NFFP + k0 + c8, &lB[c * 8]);
    }
    __syncthreads();
    #pragma unroll
    for (int kh = 0; kh < 2; kh++) {
      int ko = kh * 32 + kq;
      short8 a[4], bb[4];
      #pragma unroll
      for (int mi = 0; mi < 4; mi++)
        a[mi] = *(const short8*)&lA[(wr * 64 + mi * 16 + rl) * 64 + ko];
      #pragma unroll
      for (int ni = 0; ni < 4; ni++)
        bb[ni] = *(const short8*)&lB[(wc * 64 + ni * 16 + rl) * 64 + ko];
      #pragma unroll
      for (int mi = 0; mi < 4; mi++)
        #pragma unroll
        for (int ni = 0; ni < 4; ni++)
          acc[mi][ni] = mfma_bf16(a[mi], bb[ni], acc[mi][ni]);
    }
    __syncthreads();
  }
  #pragma unroll
  for (int mi = 0; mi < 4; mi++)
    #pragma unroll
    for (int ni = 0; ni < 4; ni++) {
      int rowg = m_base + m0l + wr * 64 + mi * 16 + (lane >> 4) * 4;
      int col = n0 + wc * 64 + ni * 16 + rl;
      #pragma unroll
      for (int r = 0; r < 4; r++) {
        size_t off = (size_t)(rowg + r) * NDIM + col;
        outp[off] = resid[off] + acc[mi][ni][r];
      }
    }
}

extern "C" void kernel_launch(void* const* d_in, const int* in_sizes, int n_in,
                              void* d_out, int out_size, void* d_ws, size_t ws_size,
                              hipStream_t stream) {
  const float* x        = (const float*)d_in[0];
  const float* in_gamma = (const float*)d_in[1];
  const float* gate_W   = (const float*)d_in[2];
  const float* cand_W   = (const float*)d_in[3];
  const float* out_W    = (const float*)d_in[4];
  const float* gbr      = (const float*)d_in[5];
  const float* gth      = (const float*)d_in[6];
  const float* cbr      = (const float*)d_in[7];
  const float* cth      = (const float*)d_in[8];
  const float* ff_gamma = (const float*)d_in[9];
  const float* ffg      = (const float*)d_in[10];
  const float* ffu      = (const float*)d_in[11];
  const float* ffd      = (const float*)d_in[12];
  float* outp = (float*)d_out;

  // ---- fixed workspace pool (~50 MB) ----
  char* p = (char*)d_ws;
  float* rscale = (float*)p;              p += 65536;
  float* state  = (float*)p;              p += 3 * NSTATE * 4;
  unsigned short* wgb = (unsigned short*)p; p += (size_t)NFFP * NDIM * 2;
  unsigned short* wub = (unsigned short*)p; p += (size_t)NFFP * NDIM * 2;
  unsigned short* wdb = (unsigned short*)p; p += (size_t)NDIM * NFFP * 2;
  unsigned short* wob = (unsigned short*)p; p += (size_t)NHEADS * NHD * NINNER * 2;
  unsigned short* fnb = (unsigned short*)p; p += (size_t)NBL * NDIM * 2;
  char* region = p;
  size_t fixed = (size_t)(region - (char*)d_ws);
  size_t avail = ws_size > fixed ? ws_size - fixed : 0;

  int CL = NL;                    // gc/cc fp32 + h bf16 = CL*122880 B
  while (CL > 128 && (size_t)CL * 122880ULL > avail) CL >>= 1;
  int MC = NBL;                   // act = MC*5632 B
  while (MC > 1024 && (size_t)MC * 5632ULL > avail) MC >>= 1;
  int LCL = 0; while ((1 << LCL) < CL) LCL++;

  float* gcb = (float*)region;
  float* ccb = (float*)(region + (size_t)CL * NSTATE * 4);
  unsigned short* hbuf = (unsigned short*)(region + (size_t)CL * NSTATE * 8);
  unsigned short* act  = (unsigned short*)region;   // phase-2 overlay

  pack_gu_kernel<<<dim3(NFFP, 2), 256, 0, stream>>>(ffg, ffu, wgb, wub);
  pack_d_kernel<<<NDIM, 256, 0, stream>>>(ffd, wdb);
  pack_flat_kernel<<<(NHEADS * NHD * NINNER + 255) / 256, 256, 0, stream>>>(
      out_W, wob, NHEADS * NHD * NINNER);
  rscale_kernel<<<NBL, 256, 0, stream>>>(x, rscale);

  int NCH = NL / CL;
  for (int c = 0; c < NCH; c++) {
    inproj_kernel<<<dim3(CL / 8, 8, 6), 256, 0, stream>>>(
        x, rscale, in_gamma, gate_W, cand_W, gcb, ccb, c * CL, LCL);
    scan_kernel<<<192, 64, 0, stream>>>(
        gcb, ccb, gbr, gth, cbr, cth, hbuf, state, (c == 0) ? 1 : 0, CL, LCL);
    outproj_kernel<<<dim3(NB * CL / 128, NHEADS), 256, 0, stream>>>(
        hbuf, wob, x, outp, c * CL, LCL);
  }

  rms_bf16_kernel<<<NBL, 256, 0, stream>>>(outp, ff_gamma, fnb);

  int NMC = NBL / MC;
  for (int mc = 0; mc < NMC; mc++) {
    int nwg_gu = (MC / 128) * 44;          // multiple of 8 for MC >= 1024
    int nwg_dn = (MC / 128) * 8;
    gateup_kernel<<<nwg_gu, 256, 0, stream>>>(fnb, wgb, wub, act, mc * MC, nwg_gu);
    down_kernel<<<nwg_dn, 256, 0, stream>>>(act, wdb, outp, outp, mc * MC, nwg_dn);
  }
}

// Round 7
// 943.936 us; speedup vs baseline: 1.1814x; 1.1814x over previous
//
#include <hip/hip_runtime.h>
#include <stdint.h>

#define NDIM   1024
#define NHEADS 8
#define NHD    128
#define NINNER 192
#define NFF    2730
#define NFFP   2816
#define NB     8
#define NL     2048
#define NBL    16384
#define NSTATE (NB * NHEADS * NINNER)   // 12288

typedef short  short8 __attribute__((ext_vector_type(8)));
typedef float  f32x4  __attribute__((ext_vector_type(4)));

__device__ __forceinline__ unsigned short f2bf(float f) {
  union { float f; uint32_t u; } v; v.f = f;
  uint32_t r = (v.u + 0x7FFFu + ((v.u >> 16) & 1u)) >> 16;
  return (unsigned short)r;
}

__device__ __forceinline__ void gload16(const void* g, void* l) {
  __builtin_amdgcn_global_load_lds(
      (const __attribute__((address_space(1))) uint32_t*)g,
      (__attribute__((address_space(3))) uint32_t*)l, 16, 0, 0);
}

__device__ __forceinline__ f32x4 mfma_bf16(short8 a, short8 b, f32x4 c) {
  return __builtin_amdgcn_mfma_f32_16x16x32_bf16(a, b, c, 0, 0, 0);
}

// ---- per-row rms scale: rscale[row] = 32 / max(||x_row||, 1e-12) -------------
__global__ __launch_bounds__(256) void rscale_kernel(
    const float* __restrict__ xin, float* __restrict__ rscale) {
  int row = blockIdx.x, t = threadIdx.x;
  float4 v = ((const float4*)(xin + (size_t)row * NDIM))[t];
  float ss = v.x * v.x + v.y * v.y + v.z * v.z + v.w * v.w;
  #pragma unroll
  for (int off = 32; off > 0; off >>= 1) ss += __shfl_xor(ss, off, 64);
  __shared__ float wss[4];
  if ((t & 63) == 0) wss[t >> 6] = ss;
  __syncthreads();
  if (t == 0) {
    ss = wss[0] + wss[1] + wss[2] + wss[3];
    rscale[row] = 32.0f / fmaxf(sqrtf(ss), 1e-12f);
  }
}

// ---- full rmsnorm -> bf16 (FFN input) ----------------------------------------
__global__ __launch_bounds__(256) void rms_bf16_kernel(
    const float* __restrict__ xin, const float* __restrict__ gamma,
    unsigned short* __restrict__ outb) {
  int row = blockIdx.x, t = threadIdx.x;
  float4 v = ((const float4*)(xin + (size_t)row * NDIM))[t];
  float ss = v.x * v.x + v.y * v.y + v.z * v.z + v.w * v.w;
  #pragma unroll
  for (int off = 32; off > 0; off >>= 1) ss += __shfl_xor(ss, off, 64);
  __shared__ float wss[4];
  if ((t & 63) == 0) wss[t >> 6] = ss;
  __syncthreads();
  ss = wss[0] + wss[1] + wss[2] + wss[3];
  float scale = 32.0f / fmaxf(sqrtf(ss), 1e-12f);
  float4 gv = ((const float4*)gamma)[t];
  ushort4 ob;
  ob.x = f2bf(v.x * scale * (1.0f + gv.x));
  ob.y = f2bf(v.y * scale * (1.0f + gv.y));
  ob.z = f2bf(v.z * scale * (1.0f + gv.z));
  ob.w = f2bf(v.w * scale * (1.0f + gv.w));
  ((ushort4*)outb)[(size_t)row * 256 + t] = ob;
}

// ---- input projections (fp32: spike round() is discontinuous) ----------------
// out layout: [(h*8 + b)*CL + ll]*192 + n   (per-(h,b) contiguous planes)
// Both LDS tiles XOR-swizzled at float4 granularity (idx4 ^= row&7):
// a-reads and w-reads are b128 and 2-way-or-broadcast = conflict-free.
__global__ __launch_bounds__(256) void inproj_kernel(
    const float* __restrict__ x, const float* __restrict__ rscale,
    const float* __restrict__ gamma, const float* __restrict__ gate_W,
    const float* __restrict__ cand_W, float* __restrict__ gcb,
    float* __restrict__ ccb, int l_base, int LCL) {
  __shared__ float lA[64 * NHD];   // 32 KB normalized x tile [64 m][128 k]
  __shared__ float lW[64 * NHD];   // 32 KB weight tile       [64 n][128 k]
  int mt = blockIdx.x, h = blockIdx.y, z = blockIdx.z;
  int branch = z / 3, nt = z % 3, n0 = nt * 64;
  const float* W = (branch == 0 ? gate_W : cand_W)
                 + (size_t)h * NINNER * NHD + (size_t)n0 * NHD;
  float* outp = (branch == 0 ? gcb : ccb);
  int t = threadIdx.x;
  #pragma unroll
  for (int i = 0; i < 8; i++) {
    int c = t + i * 256;
    int r = c >> 5, c4 = c & 31;
    int m = mt * 64 + r, ll = m >> 3, b = m & 7;
    int xrow = b * NL + l_base + ll;
    float4 xv = *(const float4*)(x + (size_t)xrow * NDIM + h * NHD + c4 * 4);
    float rs = rscale[xrow];
    float4 gv = *(const float4*)(gamma + h * NHD + c4 * 4);
    float4 o;
    o.x = xv.x * rs * (1.0f + gv.x);
    o.y = xv.y * rs * (1.0f + gv.y);
    o.z = xv.z * rs * (1.0f + gv.z);
    o.w = xv.w * rs * (1.0f + gv.w);
    *(float4*)&lA[r * NHD + ((c4 ^ (r & 7)) * 4)] = o;
    *(float4*)&lW[r * NHD + ((c4 ^ (r & 7)) * 4)] =
        *(const float4*)(W + (size_t)r * NHD + c4 * 4);
  }
  __syncthreads();
  int tr = t >> 4, tc = t & 15;
  int wkey = tc & 7;
  float acc[4][4] = {};
  #pragma unroll 4
  for (int k4 = 0; k4 < 32; k4++) {
    float4 a[4], w[4];
    #pragma unroll
    for (int m = 0; m < 4; m++) {
      int row = tr * 4 + m;
      a[m] = *(float4*)&lA[row * NHD + ((k4 ^ (row & 7)) * 4)];
    }
    #pragma unroll
    for (int j = 0; j < 4; j++)
      w[j] = *(const float4*)&lW[(tc + 16 * j) * NHD + ((k4 ^ wkey) * 4)];
    #pragma unroll
    for (int m = 0; m < 4; m++)
      #pragma unroll
      for (int j = 0; j < 4; j++) {
        acc[m][j] = fmaf(a[m].x, w[j].x, acc[m][j]);
        acc[m][j] = fmaf(a[m].y, w[j].y, acc[m][j]);
        acc[m][j] = fmaf(a[m].z, w[j].z, acc[m][j]);
        acc[m][j] = fmaf(a[m].w, w[j].w, acc[m][j]);
      }
  }
  #pragma unroll
  for (int m = 0; m < 4; m++) {
    int mm = mt * 64 + tr * 4 + m;
    int ll = mm >> 3, b = mm & 7;
    size_t rowo = ((size_t)((h * NB + b) << LCL) + ll) * NINNER + n0 + tc;
    #pragma unroll
    for (int j = 0; j < 4; j++) outp[rowo + 16 * j] = acc[m][j];
  }
}

// ---- sequential spiking minGRU scan (192 blocks x 64 thr, CH=32) -------------
__global__ __launch_bounds__(64) void scan_kernel(
    const float* __restrict__ gcb, const float* __restrict__ ccb,
    const float* __restrict__ gbr, const float* __restrict__ gth,
    const float* __restrict__ cbr, const float* __restrict__ cth,
    unsigned short* __restrict__ hbuf, float* __restrict__ state,
    int first, int CL, int LCL) {
  int bh = blockIdx.x / 3, third = blockIdx.x % 3;
  int b = bh >> 3, h = bh & 7;
  int i = third * 64 + threadIdx.x;
  int pi = h * NINNER + i;
  float beta_g = 1.0f / (1.0f + expf(-gbr[pi]));
  float beta_c = 1.0f / (1.0f + expf(-cbr[pi]));
  float thg = gth[pi], thc = cth[pi];
  size_t sbase = ((size_t)(b * NHEADS + h)) * NINNER + i;
  size_t pbase = ((size_t)((h * NB + b) << LCL)) * NINNER + i;
  const float* pg = gcb + pbase;
  const float* pc = ccb + pbase;
  unsigned short* ph = hbuf + pbase;
  float gm, cm, hs;
  if (first) { gm = 0.f; cm = 0.f; hs = 0.f; }
  else { gm = state[sbase]; cm = state[NSTATE + sbase]; hs = state[2 * NSTATE + sbase]; }
  const int CH = 32;
  float gq[CH], cq[CH];
  #pragma unroll
  for (int u = 0; u < CH; u++) { gq[u] = pg[u * NINNER]; cq[u] = pc[u * NINNER]; }
  int NIT = CL / CH;
  for (int ch = 0; ch < NIT; ch++) {
    float gn[CH], cn[CH];
    bool more = (ch + 1) < NIT;
    if (more) {
      size_t nb = (size_t)(ch + 1) * CH * NINNER;
      #pragma unroll
      for (int u = 0; u < CH; u++) { gn[u] = pg[nb + u * NINNER]; cn[u] = pc[nb + u * NINNER]; }
    }
    #pragma unroll
    for (int u = 0; u < CH; u++) {
      gm = fmaf(beta_g, gm, gq[u]);
      float gs = fminf(fmaxf(rintf(gm), -1.f), 1.f);
      gm -= gs * thg;
      float z = (gs + 1.f) * 0.5f;
      cm = fmaf(beta_c, cm, cq[u]);
      float cs = fminf(fmaxf(rintf(cm), -1.f), 1.f);
      cm -= cs * thc;
      hs = (1.f - z) * hs + z * cs;
      ph[((size_t)(ch * CH + u)) * NINNER] = f2bf(hs);
    }
    if (more) {
      #pragma unroll
      for (int u = 0; u < CH; u++) { gq[u] = gn[u]; cq[u] = cn[u]; }
    }
  }
  state[sbase] = gm; state[NSTATE + sbase] = cm; state[2 * NSTATE + sbase] = hs;
}

// ---- output projection as bf16 MFMA + residual: x2 = x + h @ out_W^T ---------
__global__ __launch_bounds__(256) void outproj_kernel(
    const unsigned short* __restrict__ hbuf, const unsigned short* __restrict__ wob,
    const float* __restrict__ x, float* __restrict__ x2, int l_base, int LCL) {
  __shared__ short lA[128 * 32], lB[128 * 32];  // 16 KB
  int t = threadIdx.x, lane = t & 63, wave = t >> 6;
  int wr = wave >> 1, wc = wave & 1;
  int m0 = blockIdx.x * 128;
  int h = blockIdx.y;
  const unsigned short* Ab = hbuf + ((size_t)(h * NB) << LCL) * NINNER;
  const unsigned short* Bb = wob + (size_t)h * NHD * NINNER;
  f32x4 z4 = {0.f, 0.f, 0.f, 0.f};
  f32x4 acc[4][4];
  #pragma unroll
  for (int i = 0; i < 4; i++)
    #pragma unroll
    for (int j = 0; j < 4; j++) acc[i][j] = z4;
  int rl = lane & 15, kq = (lane >> 4) * 8;
  for (int ks = 0; ks < NINNER / 32; ks++) {
    int k0 = ks * 32;
    #pragma unroll
    for (int it = 0; it < 2; it++) {
      int c = t + it * 256;
      int r = c >> 2, c8 = (c & 3) * 8;
      gload16(Ab + (size_t)(m0 + r) * NINNER + k0 + c8, &lA[c * 8]);
      gload16(Bb + (size_t)r * NINNER + k0 + c8, &lB[c * 8]);
    }
    __syncthreads();
    short8 a[4], bb[4];
    #pragma unroll
    for (int mi = 0; mi < 4; mi++)
      a[mi] = *(const short8*)&lA[(wr * 64 + mi * 16 + rl) * 32 + kq];
    #pragma unroll
    for (int ni = 0; ni < 4; ni++)
      bb[ni] = *(const short8*)&lB[(wc * 64 + ni * 16 + rl) * 32 + kq];
    #pragma unroll
    for (int mi = 0; mi < 4; mi++)
      #pragma unroll
      for (int ni = 0; ni < 4; ni++)
        acc[mi][ni] = mfma_bf16(a[mi], bb[ni], acc[mi][ni]);
    __syncthreads();
  }
  int CLm1 = (1 << LCL) - 1;
  #pragma unroll
  for (int mi = 0; mi < 4; mi++)
    #pragma unroll
    for (int ni = 0; ni < 4; ni++) {
      int rowl = m0 + wr * 64 + mi * 16 + (lane >> 4) * 4;
      int col = wc * 64 + ni * 16 + rl;
      #pragma unroll
      for (int r = 0; r < 4; r++) {
        int rr = rowl + r;
        int b = rr >> LCL, ll = rr & CLm1;
        size_t off = ((size_t)(b * NL + l_base + ll)) * NDIM + h * NHD + col;
        x2[off] = x[off] + acc[mi][ni][r];
      }
    }
}

// ---- weight packs ------------------------------------------------------------
__global__ __launch_bounds__(256) void pack_gu_kernel(
    const float* __restrict__ ffg, const float* __restrict__ ffu,
    unsigned short* __restrict__ wg, unsigned short* __restrict__ wu) {
  int row = blockIdx.x, t = threadIdx.x;
  const float* src = (blockIdx.y == 0) ? ffg : ffu;
  unsigned short* dst = (blockIdx.y == 0) ? wg : wu;
  ushort4 o;
  if (row < NFF) {
    float4 v = *(const float4*)(src + (size_t)row * NDIM + t * 4);
    o.x = f2bf(v.x); o.y = f2bf(v.y); o.z = f2bf(v.z); o.w = f2bf(v.w);
  } else { o.x = 0; o.y = 0; o.z = 0; o.w = 0; }
  *(ushort4*)(dst + (size_t)row * NDIM + t * 4) = o;
}

__global__ __launch_bounds__(256) void pack_d_kernel(
    const float* __restrict__ ffd, unsigned short* __restrict__ wd) {
  int row = blockIdx.x;
  for (int c = threadIdx.x; c < NFFP; c += 256) {
    float v = (c < NFF) ? ffd[(size_t)row * NFF + c] : 0.0f;
    wd[(size_t)row * NFFP + c] = f2bf(v);
  }
}

__global__ __launch_bounds__(256) void pack_flat_kernel(
    const float* __restrict__ src, unsigned short* __restrict__ dst, int n) {
  int i = blockIdx.x * 256 + threadIdx.x;
  if (i < n) dst[i] = f2bf(src[i]);
}

// ---- FFN gate+up bf16 MFMA GEMM, fused silu(g)*u (r5 geometry: BK=32) --------
// 128(M) x 64(N) tile; per-wave 64x32 dual-acc (64 acc regs) = m97 reg profile.
__global__ __launch_bounds__(256) void gateup_kernel(
    const unsigned short* __restrict__ fnb, const unsigned short* __restrict__ wg,
    const unsigned short* __restrict__ wu, unsigned short* __restrict__ act,
    int m_base, int nwg) {
  __shared__ short lA[128 * 32], lG[64 * 32], lU[64 * 32];  // 16 KB
  int q = nwg >> 3;
  int hw = blockIdx.x;
  int work = (hw & 7) * q + (hw >> 3);
  int mt = work / 44, ntl = work % 44;
  int t = threadIdx.x, lane = t & 63, wave = t >> 6;
  int wr = wave >> 1, wc = wave & 1;
  int m0l = mt * 128;
  int m0g = m_base + m0l;
  int n0 = ntl * 64;
  f32x4 z4 = {0.f, 0.f, 0.f, 0.f};
  f32x4 accg[4][2], accu[4][2];
  #pragma unroll
  for (int i = 0; i < 4; i++)
    #pragma unroll
    for (int j = 0; j < 2; j++) { accg[i][j] = z4; accu[i][j] = z4; }
  int rl = lane & 15, kq = (lane >> 4) * 8;
  for (int ks = 0; ks < NDIM / 32; ks++) {
    int k0 = ks * 32;
    {
      #pragma unroll
      for (int it = 0; it < 2; it++) {
        int c = t + it * 256;
        int r = c >> 2, c8 = (c & 3) * 8;
        gload16(fnb + (size_t)(m0g + r) * NDIM + k0 + c8, &lA[c * 8]);
      }
      int r = t >> 2, c8 = (t & 3) * 8;
      gload16(wg + (size_t)(n0 + r) * NDIM + k0 + c8, &lG[t * 8]);
      gload16(wu + (size_t)(n0 + r) * NDIM + k0 + c8, &lU[t * 8]);
    }
    __syncthreads();
    short8 a[4], bg[2], bu[2];
    #pragma unroll
    for (int mi = 0; mi < 4; mi++)
      a[mi] = *(const short8*)&lA[(wr * 64 + mi * 16 + rl) * 32 + kq];
    #pragma unroll
    for (int ni = 0; ni < 2; ni++) {
      bg[ni] = *(const short8*)&lG[(wc * 32 + ni * 16 + rl) * 32 + kq];
      bu[ni] = *(const short8*)&lU[(wc * 32 + ni * 16 + rl) * 32 + kq];
    }
    #pragma unroll
    for (int mi = 0; mi < 4; mi++)
      #pragma unroll
      for (int ni = 0; ni < 2; ni++) {
        accg[mi][ni] = mfma_bf16(a[mi], bg[ni], accg[mi][ni]);
        accu[mi][ni] = mfma_bf16(a[mi], bu[ni], accu[mi][ni]);
      }
    __syncthreads();
  }
  #pragma unroll
  for (int mi = 0; mi < 4; mi++)
    #pragma unroll
    for (int ni = 0; ni < 2; ni++) {
      int rowl = m0l + wr * 64 + mi * 16 + (lane >> 4) * 4;
      int col = n0 + wc * 32 + ni * 16 + rl;
      #pragma unroll
      for (int r = 0; r < 4; r++) {
        float g = accg[mi][ni][r], u = accu[mi][ni][r];
        float s = g / (1.0f + expf(-g)) * u;
        act[(size_t)(rowl + r) * NFFP + col] = f2bf(s);
      }
    }
}

// ---- FFN down bf16 MFMA GEMM + residual (r5 geometry: BK=32) -----------------
__global__ __launch_bounds__(256) void down_kernel(
    const unsigned short* __restrict__ act, const unsigned short* __restrict__ wd,
    const float* resid, float* outp, int m_base, int nwg) {
  __shared__ short lA[128 * 32], lB[128 * 32];  // 16 KB
  int q = nwg >> 3;
  int hw = blockIdx.x;
  int work = (hw & 7) * q + (hw >> 3);
  int mt = work >> 3, ntl = work & 7;
  int t = threadIdx.x, lane = t & 63, wave = t >> 6;
  int wr = wave >> 1, wc = wave & 1;
  int m0l = mt * 128;
  int n0 = ntl * 128;
  f32x4 z4 = {0.f, 0.f, 0.f, 0.f};
  f32x4 acc[4][4];
  #pragma unroll
  for (int i = 0; i < 4; i++)
    #pragma unroll
    for (int j = 0; j < 4; j++) acc[i][j] = z4;
  int rl = lane & 15, kq = (lane >> 4) * 8;
  for (int ks = 0; ks < NFFP / 32; ks++) {
    int k0 = ks * 32;
    #pragma unroll
    for (int it = 0; it < 2; it++) {
      int c = t + it * 256;
      int r = c >> 2, c8 = (c & 3) * 8;
      gload16(act + (size_t)(m0l + r) * NFFP + k0 + c8, &lA[c * 8]);
      gload16(wd  + (size_t)(n0 + r) * NFFP + k0 + c8, &lB[c * 8]);
    }
    __syncthreads();
    short8 a[4], bb[4];
    #pragma unroll
    for (int mi = 0; mi < 4; mi++)
      a[mi] = *(const short8*)&lA[(wr * 64 + mi * 16 + rl) * 32 + kq];
    #pragma unroll
    for (int ni = 0; ni < 4; ni++)
      bb[ni] = *(const short8*)&lB[(wc * 64 + ni * 16 + rl) * 32 + kq];
    #pragma unroll
    for (int mi = 0; mi < 4; mi++)
      #pragma unroll
      for (int ni = 0; ni < 4; ni++)
        acc[mi][ni] = mfma_bf16(a[mi], bb[ni], acc[mi][ni]);
    __syncthreads();
  }
  #pragma unroll
  for (int mi = 0; mi < 4; mi++)
    #pragma unroll
    for (int ni = 0; ni < 4; ni++) {
      int rowg = m_base + m0l + wr * 64 + mi * 16 + (lane >> 4) * 4;
      int col = n0 + wc * 64 + ni * 16 + rl;
      #pragma unroll
      for (int r = 0; r < 4; r++) {
        size_t off = (size_t)(rowg + r) * NDIM + col;
        outp[off] = resid[off] + acc[mi][ni][r];
      }
    }
}

extern "C" void kernel_launch(void* const* d_in, const int* in_sizes, int n_in,
                              void* d_out, int out_size, void* d_ws, size_t ws_size,
                              hipStream_t stream) {
  const float* x        = (const float*)d_in[0];
  const float* in_gamma = (const float*)d_in[1];
  const float* gate_W   = (const float*)d_in[2];
  const float* cand_W   = (const float*)d_in[3];
  const float* out_W    = (const float*)d_in[4];
  const float* gbr      = (const float*)d_in[5];
  const float* gth      = (const float*)d_in[6];
  const float* cbr      = (const float*)d_in[7];
  const float* cth      = (const float*)d_in[8];
  const float* ff_gamma = (const float*)d_in[9];
  const float* ffg      = (const float*)d_in[10];
  const float* ffu      = (const float*)d_in[11];
  const float* ffd      = (const float*)d_in[12];
  float* outp = (float*)d_out;

  // ---- fixed workspace pool (~50 MB) ----
  char* p = (char*)d_ws;
  float* rscale = (float*)p;              p += 65536;
  float* state  = (float*)p;              p += 3 * NSTATE * 4;
  unsigned short* wgb = (unsigned short*)p; p += (size_t)NFFP * NDIM * 2;
  unsigned short* wub = (unsigned short*)p; p += (size_t)NFFP * NDIM * 2;
  unsigned short* wdb = (unsigned short*)p; p += (size_t)NDIM * NFFP * 2;
  unsigned short* wob = (unsigned short*)p; p += (size_t)NHEADS * NHD * NINNER * 2;
  unsigned short* fnb = (unsigned short*)p; p += (size_t)NBL * NDIM * 2;
  char* region = p;
  size_t fixed = (size_t)(region - (char*)d_ws);
  size_t avail = ws_size > fixed ? ws_size - fixed : 0;

  int CL = NL;                    // gc/cc fp32 + h bf16 = CL*122880 B
  while (CL > 128 && (size_t)CL * 122880ULL > avail) CL >>= 1;
  int MC = NBL;                   // act = MC*5632 B
  while (MC > 1024 && (size_t)MC * 5632ULL > avail) MC >>= 1;
  int LCL = 0; while ((1 << LCL) < CL) LCL++;

  float* gcb = (float*)region;
  float* ccb = (float*)(region + (size_t)CL * NSTATE * 4);
  unsigned short* hbuf = (unsigned short*)(region + (size_t)CL * NSTATE * 8);
  unsigned short* act  = (unsigned short*)region;   // phase-2 overlay

  pack_gu_kernel<<<dim3(NFFP, 2), 256, 0, stream>>>(ffg, ffu, wgb, wub);
  pack_d_kernel<<<NDIM, 256, 0, stream>>>(ffd, wdb);
  pack_flat_kernel<<<(NHEADS * NHD * NINNER + 255) / 256, 256, 0, stream>>>(
      out_W, wob, NHEADS * NHD * NINNER);
  rscale_kernel<<<NBL, 256, 0, stream>>>(x, rscale);

  int NCH = NL / CL;
  for (int c = 0; c < NCH; c++) {
    inproj_kernel<<<dim3(CL / 8, 8, 6), 256, 0, stream>>>(
        x, rscale, in_gamma, gate_W, cand_W, gcb, ccb, c * CL, LCL);
    scan_kernel<<<192, 64, 0, stream>>>(
        gcb, ccb, gbr, gth, cbr, cth, hbuf, state, (c == 0) ? 1 : 0, CL, LCL);
    outproj_kernel<<<dim3(NB * CL / 128, NHEADS), 256, 0, stream>>>(
        hbuf, wob, x, outp, c * CL, LCL);
  }

  rms_bf16_kernel<<<NBL, 256, 0, stream>>>(outp, ff_gamma, fnb);

  int NMC = NBL / MC;
  for (int mc = 0; mc < NMC; mc++) {
    int nwg_gu = (MC / 128) * 44;          // multiple of 8 for MC >= 1024
    int nwg_dn = (MC / 128) * 8;
    gateup_kernel<<<nwg_gu, 256, 0, stream>>>(fnb, wgb, wub, act, mc * MC, nwg_gu);
    down_kernel<<<nwg_dn, 256, 0, stream>>>(act, wdb, outp, outp, mc * MC, nwg_dn);
  }
}